// Round 11
// baseline (810.110 us; speedup 1.0000x reference)
//
#include <hip/hip_runtime.h>
#include <hip/hip_bf16.h>
#include <stdint.h>

#define TOKENS 8192
#define IN_F   4096
#define OUT_F  4096
#define GROUP  128

typedef __attribute__((ext_vector_type(4))) int   i32x4;
typedef __attribute__((ext_vector_type(4))) float f32x4;

// ---------------------------------------------------------------------------
// Kernel 1: quantize x rows to int8 with per-token scale. out = xs[m]*xq.
// ---------------------------------------------------------------------------
__global__ __launch_bounds__(256) void k_quant_x(const float* __restrict__ x,
                                                 int8_t* __restrict__ xq,
                                                 float* __restrict__ xs) {
  const int row = blockIdx.x;
  const int t = threadIdx.x;
  const float4* xr = (const float4*)(x + (size_t)row * IN_F) + t * 4;
  float f[16];
  *(float4*)&f[0] = xr[0];
  *(float4*)&f[4] = xr[1];
  *(float4*)&f[8] = xr[2];
  *(float4*)&f[12] = xr[3];
  float am = 0.f;
#pragma unroll
  for (int j = 0; j < 16; ++j) am = fmaxf(am, fabsf(f[j]));
#pragma unroll
  for (int off = 32; off; off >>= 1) am = fmaxf(am, __shfl_xor(am, off));
  __shared__ float red[4];
  if ((t & 63) == 0) red[t >> 6] = am;
  __syncthreads();
  am = fmaxf(fmaxf(red[0], red[1]), fmaxf(red[2], red[3]));
  am = fmaxf(am, 1e-8f);
  const float inv = 127.f / am;
  if (t == 0) xs[row] = am / 127.f;
  union {
    i32x4 v;
    int8_t c[16];
  } u;
#pragma unroll
  for (int j = 0; j < 16; ++j) u.c[j] = (int8_t)__float2int_rn(f[j] * inv);
  ((i32x4*)(xq + (size_t)row * IN_F))[t] = u.v;
}

// ---------------------------------------------------------------------------
// Kernel 2: unpack weights -> W'^T int8 [OUT_F][IN_F], w' = w - z (exact).
// ---------------------------------------------------------------------------
__global__ __launch_bounds__(256) void k_dequant_w8(
    const int* __restrict__ qweight, const int* __restrict__ qzeros,
    int8_t* __restrict__ wq) {
  __shared__ __align__(16) int8_t sW[256][80];  // [n][k 64 + 16 pad]
  const int nt = blockIdx.x & 15;   // 16 n-tiles
  const int kt = blockIdx.x >> 4;   // 64 k-tiles
  const int n0 = nt * 256;
  const int k0 = kt * 64;
  const int g = k0 / GROUP;
  const int t = threadIdx.x;
  const int n = n0 + t;

  const unsigned zw =
      ((const unsigned*)qzeros)[(size_t)g * (OUT_F / 8) + (n >> 3)];
  const int z = (int)((zw >> ((n & 7) * 4)) & 15u);
  const int kw0 = k0 >> 3;
#pragma unroll
  for (int kw = 0; kw < 8; ++kw) {
    const unsigned w = ((const unsigned*)qweight)[(size_t)(kw0 + kw) * OUT_F + n];
#pragma unroll
    for (int j = 0; j < 8; ++j) {
      const int q = (int)((w >> (4 * j)) & 15u);
      sW[t][kw * 8 + j] = (int8_t)(q - z);
    }
  }
  __syncthreads();
#pragma unroll
  for (int pass = 0; pass < 4; ++pass) {
    const int row = pass * 64 + (t >> 2);
    const int kc = t & 3;
    i32x4 v = *(const i32x4*)&sW[row][kc * 16];
    *(i32x4*)(wq + (size_t)(n0 + row) * IN_F + k0 + kc * 16) = v;
  }
}

// ---------------------------------------------------------------------------
// Kernel 3: int8 MFMA GEMM, block 128x128, 8 waves (2M x 4N), wave 64x32.
// LDS = 2 bufs x (A16K + B16K) + s-table 8K = 72 KB -> 2 blocks/CU;
// __launch_bounds__(512,4) -> 4 waves/SIMD. Round-11 FIX: round-10 staged
// into the just-read buffer guarded only by the wave's own lgkmcnt(0) —
// cross-wave WAR race (leading wave's DMA returns ~200cy from L2-resident
// B panel and overwrites rows a lagging wave hasn't read). Restore the
// rounds-5..9 invariant with a block-wide s_barrier between reads and the
// same-buffer STAGE:
//   reads -> lgkm(0) -> barrier -> STAGE T+2 -> MFMA+DEQ -> vmcnt(4) -> barrier
// vmcnt(4) still drains exactly the next phase's tile (8 outstanding -> 4).
// ---------------------------------------------------------------------------
__device__ inline void gload_lds16(const void* g, void* l) {
  __builtin_amdgcn_global_load_lds(
      (const __attribute__((address_space(1))) void*)g,
      (__attribute__((address_space(3))) void*)l, 16, 0, 0);
}

// stage tile (A 2 + B 2 gloads) into buf
#define STAGE_T(buf, tile)                                                    \
  do {                                                                        \
    _Pragma("unroll") for (int r_ = 0; r_ < 2; ++r_) {                        \
      gload_lds16(Ag + goff[r_] + (size_t)((tile) & 31) * 128,                \
                  smem + (buf)*32768 + ldsoff[r_]);                           \
    }                                                                         \
    _Pragma("unroll") for (int r_ = 0; r_ < 2; ++r_) {                        \
      gload_lds16(Bg + goff[r_] + (size_t)((tile) & 31) * 128,                \
                  smem + (buf)*32768 + 16384 + ldsoff[r_]);                   \
    }                                                                         \
  } while (0)

// one K=128 tile (= one quant group)
#define PHASE(bufc, T, TP)                                                    \
  do {                                                                        \
    _Pragma("unroll") for (int nf_ = 0; nf_ < 2; ++nf_) {                     \
      const char* p_ =                                                        \
          smem + (bufc)*32768 + 16384 + (wc * 32 + nf_ * 16 + fr) * 128;      \
      bF[nf_][0] = *(const i32x4*)(p_ + csw0);                                \
      bF[nf_][1] = *(const i32x4*)(p_ + csw1);                                \
    }                                                                         \
    _Pragma("unroll") for (int mf_ = 0; mf_ < 4; ++mf_) {                     \
      const char* p_ = smem + (bufc)*32768 + (wr * 64 + mf_ * 16 + fr) * 128; \
      aF[mf_][0] = *(const i32x4*)(p_ + csw0);                                \
      aF[mf_][1] = *(const i32x4*)(p_ + csw1);                                \
    }                                                                         \
    _Pragma("unroll") for (int nf_ = 0; nf_ < 2; ++nf_) {                     \
      sF[nf_] = *reinterpret_cast<const unsigned short*>(                     \
          smem + 65536 + (((T)&31) * 128 + wc * 32 + nf_ * 16 + fr) * 2);     \
    }                                                                         \
    asm volatile("s_waitcnt lgkmcnt(0)" ::: "memory");                        \
    __builtin_amdgcn_sched_barrier(0);                                        \
    __builtin_amdgcn_s_barrier(); /* all waves' reads of bufc done */         \
    STAGE_T(bufc, TP);            /* safe to overwrite bufc now */            \
    __builtin_amdgcn_s_setprio(1);                                            \
    _Pragma("unroll") for (int nf_ = 0; nf_ < 2; ++nf_) {                     \
      i32x4 iacc[4];                                                          \
      _Pragma("unroll") for (int mf_ = 0; mf_ < 4; ++mf_) {                   \
        iacc[mf_] = __builtin_amdgcn_mfma_i32_16x16x64_i8(                    \
            aF[mf_][0], bF[nf_][0], zero4, 0, 0, 0);                          \
      }                                                                       \
      _Pragma("unroll") for (int mf_ = 0; mf_ < 4; ++mf_) {                   \
        iacc[mf_] = __builtin_amdgcn_mfma_i32_16x16x64_i8(                    \
            aF[mf_][1], bF[nf_][1], iacc[mf_], 0, 0, 0);                      \
      }                                                                       \
      const float sv_ = __uint_as_float((unsigned)sF[nf_] << 16);             \
      _Pragma("unroll") for (int mf_ = 0; mf_ < 4; ++mf_)                     \
          _Pragma("unroll") for (int r_ = 0; r_ < 4; ++r_) {                  \
        facc[mf_][nf_][r_] += sv_ * (float)iacc[mf_][r_];                     \
      }                                                                       \
    }                                                                         \
    __builtin_amdgcn_s_setprio(0);                                            \
    __builtin_amdgcn_sched_barrier(0);                                        \
    asm volatile("s_waitcnt vmcnt(4)" ::: "memory");                          \
    __builtin_amdgcn_s_barrier();                                             \
  } while (0)

__global__ __launch_bounds__(512, 4) void k_gemm_i8(
    const int8_t* __restrict__ xq,    // [TOKENS][IN_F]
    const int8_t* __restrict__ wq,    // [OUT_F][IN_F]
    const float* __restrict__ scales, // [32][OUT_F]
    const float* __restrict__ xs,     // [TOKENS]
    const float* __restrict__ bias,   // [OUT_F]
    float* __restrict__ out) {        // [TOKENS][OUT_F]
  extern __shared__ __align__(16) char smem[];  // 73728 B

  // XCD chunking: xcd gets 8 bm x 32 bn; 2 bm co-resident per round.
  const int bidx = blockIdx.x;
  const int xcd = bidx & 7;
  const int slot = bidx >> 3;             // 0..255
  const int bm = xcd * 8 + (slot >> 5);   // 0..63
  const int bn = slot & 31;               // 0..31
  const int m0 = bm * 128;
  const int n0 = bn * 128;

  const int t = threadIdx.x;
  const int lane = t & 63;
  const int wid = t >> 6;    // 8 waves
  const int wr = wid >> 2;   // 2 (M)
  const int wc = wid & 3;    // 4 (N)
  const int fr = lane & 15;
  const int hq = lane >> 4;  // k-quarter (16 int8)

  const int csw0 = (hq ^ (fr & 7)) * 16;
  const int csw1 = ((hq ^ (fr & 7)) ^ 4) * 16;

  int goff[2], ldsoff[2];
#pragma unroll
  for (int r = 0; r < 2; ++r) {
    const int srow = r * 64 + wid * 8 + (lane >> 3);  // 0..127
    const int schunk = (lane & 7) ^ (srow & 7);       // inverse swizzle
    goff[r] = srow * IN_F + schunk * 16;
    ldsoff[r] = (r * 512 + wid * 64) * 16;            // wave-uniform
  }

  const char* Ag = (const char*)(xq + (size_t)m0 * IN_F);
  const char* Bg = (const char*)(wq + (size_t)n0 * IN_F);

  // s-table: [32 g][128 cols] bf16 at smem+65536
#pragma unroll
  for (int j = 0; j < 8; ++j) {
    const int idx = t * 8 + j;  // 0..4095
    const int g = idx >> 7, c = idx & 127;
    *reinterpret_cast<unsigned short*>(smem + 65536 + idx * 2) =
        __bfloat16_as_ushort(__float2bfloat16(scales[(size_t)g * OUT_F + n0 + c]));
  }

  f32x4 facc[4][2];
#pragma unroll
  for (int i = 0; i < 4; ++i)
#pragma unroll
    for (int j = 0; j < 2; ++j) facc[i][j] = (f32x4){0.f, 0.f, 0.f, 0.f};
  const i32x4 zero4 = {0, 0, 0, 0};

  i32x4 aF[4][2];
  i32x4 bF[2][2];
  unsigned short sF[2];

  // ---- prologue: stage tiles 0 (buf0), 1 (buf1); drain tile0 + s-table.
  STAGE_T(0, 0);
  STAGE_T(1, 1);
  asm volatile("s_waitcnt vmcnt(4) lgkmcnt(0)" ::: "memory");
  __builtin_amdgcn_s_barrier();

  // ---- main loop: 32 tiles (= groups), 1 phase each, bufs alternate.
#pragma unroll 1
  for (int it = 0; it < 16; ++it) {
    const int T = 2 * it;
    PHASE(0, T, T + 2);
    PHASE(1, T + 1, T + 3);
  }

  // ---- epilogue: out = xs[m]*facc + bias[n]
  float bv[2];
#pragma unroll
  for (int nf = 0; nf < 2; ++nf) bv[nf] = bias[n0 + wc * 32 + nf * 16 + fr];
#pragma unroll
  for (int mf = 0; mf < 4; ++mf) {
#pragma unroll
    for (int r = 0; r < 4; ++r) {
      const int m = m0 + wr * 64 + mf * 16 + hq * 4 + r;
      const float xsv = xs[m];
      float* o = out + (size_t)m * OUT_F + n0;
#pragma unroll
      for (int nf = 0; nf < 2; ++nf) {
        o[wc * 32 + nf * 16 + fr] = xsv * facc[mf][nf][r] + bv[nf];
      }
    }
  }
}

// ---------------------------------------------------------------------------
extern "C" void kernel_launch(void* const* d_in, const int* in_sizes, int n_in,
                              void* d_out, int out_size, void* d_ws,
                              size_t ws_size, hipStream_t stream) {
  const float* x = (const float*)d_in[0];
  const int* qweight = (const int*)d_in[1];
  const int* qzeros = (const int*)d_in[2];
  const float* scales = (const float*)d_in[3];
  const float* bias = (const float*)d_in[4];
  float* out = (float*)d_out;

  int8_t* xq = (int8_t*)d_ws;                          // 32 MiB
  int8_t* wq = xq + (size_t)TOKENS * IN_F;             // +16 MiB
  float* xs = (float*)(wq + (size_t)OUT_F * IN_F);     // +32 KiB

  (void)hipFuncSetAttribute(reinterpret_cast<const void*>(&k_gemm_i8),
                            hipFuncAttributeMaxDynamicSharedMemorySize, 73728);

  k_quant_x<<<TOKENS, 256, 0, stream>>>(x, xq, xs);
  k_dequant_w8<<<1024, 256, 0, stream>>>(qweight, qzeros, wq);
  k_gemm_i8<<<(TOKENS / 128) * (OUT_F / 128), 512, 73728, stream>>>(
      xq, wq, scales, xs, bias, out);
}

// Round 12
// 277.029 us; speedup vs baseline: 2.9243x; 2.9243x over previous
//
#include <hip/hip_runtime.h>
#include <hip/hip_bf16.h>
#include <stdint.h>

#define TOKENS 8192
#define IN_F   4096
#define OUT_F  4096
#define GROUP  128

typedef __attribute__((ext_vector_type(4))) int   i32x4;
typedef __attribute__((ext_vector_type(4))) float f32x4;

// ---------------------------------------------------------------------------
// Kernel 1: quantize x rows to int8 with per-token scale. out = xs[m]*xq.
// ---------------------------------------------------------------------------
__global__ __launch_bounds__(256) void k_quant_x(const float* __restrict__ x,
                                                 int8_t* __restrict__ xq,
                                                 float* __restrict__ xs) {
  const int row = blockIdx.x;
  const int t = threadIdx.x;
  const float4* xr = (const float4*)(x + (size_t)row * IN_F) + t * 4;
  float f[16];
  *(float4*)&f[0] = xr[0];
  *(float4*)&f[4] = xr[1];
  *(float4*)&f[8] = xr[2];
  *(float4*)&f[12] = xr[3];
  float am = 0.f;
#pragma unroll
  for (int j = 0; j < 16; ++j) am = fmaxf(am, fabsf(f[j]));
#pragma unroll
  for (int off = 32; off; off >>= 1) am = fmaxf(am, __shfl_xor(am, off));
  __shared__ float red[4];
  if ((t & 63) == 0) red[t >> 6] = am;
  __syncthreads();
  am = fmaxf(fmaxf(red[0], red[1]), fmaxf(red[2], red[3]));
  am = fmaxf(am, 1e-8f);
  const float inv = 127.f / am;
  if (t == 0) xs[row] = am / 127.f;
  union {
    i32x4 v;
    int8_t c[16];
  } u;
#pragma unroll
  for (int j = 0; j < 16; ++j) u.c[j] = (int8_t)__float2int_rn(f[j] * inv);
  ((i32x4*)(xq + (size_t)row * IN_F))[t] = u.v;
}

// ---------------------------------------------------------------------------
// Kernel 2: unpack weights -> W'^T int8 [OUT_F][IN_F], w' = w - z (exact).
// ---------------------------------------------------------------------------
__global__ __launch_bounds__(256) void k_dequant_w8(
    const int* __restrict__ qweight, const int* __restrict__ qzeros,
    int8_t* __restrict__ wq) {
  __shared__ __align__(16) int8_t sW[256][80];  // [n][k 64 + 16 pad]
  const int nt = blockIdx.x & 15;   // 16 n-tiles
  const int kt = blockIdx.x >> 4;   // 64 k-tiles
  const int n0 = nt * 256;
  const int k0 = kt * 64;
  const int g = k0 / GROUP;
  const int t = threadIdx.x;
  const int n = n0 + t;

  const unsigned zw =
      ((const unsigned*)qzeros)[(size_t)g * (OUT_F / 8) + (n >> 3)];
  const int z = (int)((zw >> ((n & 7) * 4)) & 15u);
  const int kw0 = k0 >> 3;
#pragma unroll
  for (int kw = 0; kw < 8; ++kw) {
    const unsigned w = ((const unsigned*)qweight)[(size_t)(kw0 + kw) * OUT_F + n];
#pragma unroll
    for (int j = 0; j < 8; ++j) {
      const int q = (int)((w >> (4 * j)) & 15u);
      sW[t][kw * 8 + j] = (int8_t)(q - z);
    }
  }
  __syncthreads();
#pragma unroll
  for (int pass = 0; pass < 4; ++pass) {
    const int row = pass * 64 + (t >> 2);
    const int kc = t & 3;
    i32x4 v = *(const i32x4*)&sW[row][kc * 16];
    *(i32x4*)(wq + (size_t)(n0 + row) * IN_F + k0 + kc * 16) = v;
  }
}

// ---------------------------------------------------------------------------
// Kernel 3: int8 MFMA GEMM. Round-12: 3 blocks/CU occupancy WITHOUT the
// round-11 spill. Block 128x64, 256 thr = 4 waves (2M x 2N), wave 64x32.
// LDS = 2 bufs x (A 16K + B 8K) = 48 KB -> 3 blocks/CU (144 <= 160);
// __launch_bounds__(256,3) -> 170-reg cap (true need ~120, no spill).
// 3 waves/SIMD from 3 UNSYNCHRONIZED blocks hide each other's stalls.
// Scales: no LDS table; 2 f32 global loads per tile, register-prefetched
// one phase ahead (sA/sB ping-pong, static names). vmcnt: each phase
// issues 6 stage + 2 scale = 8 VMEM; end-of-phase vmcnt(8) keeps own 8,
// drains previous tile's stage. WAR: reads -> lgkm(0) -> barrier ->
// same-buf STAGE (round-11's proven-correct invariant).
// ---------------------------------------------------------------------------
__device__ inline void gload_lds16(const void* g, void* l) {
  __builtin_amdgcn_global_load_lds(
      (const __attribute__((address_space(1))) void*)g,
      (__attribute__((address_space(3))) void*)l, 16, 0, 0);
}

// stage tile (A 4 + B 2 gloads per wave) into buf
#define STAGE_T(buf, tile)                                                    \
  do {                                                                        \
    _Pragma("unroll") for (int i_ = 0; i_ < 4; ++i_) {                        \
      gload_lds16(Ag + goffA[i_] + (size_t)((tile) & 31) * 128,               \
                  smem + (buf)*24576 + ldsA[i_]);                             \
    }                                                                         \
    _Pragma("unroll") for (int i_ = 0; i_ < 2; ++i_) {                        \
      gload_lds16(Bg + goffB[i_] + (size_t)((tile) & 31) * 128,               \
                  smem + (buf)*24576 + ldsB[i_]);                             \
    }                                                                         \
  } while (0)

// one K=128 tile (= one quant group); sC: scales for T (ready),
// sN: loads scales for T+1 (consumed next phase).
#define PHASE(bufc, T, sC, sN)                                                \
  do {                                                                        \
    _Pragma("unroll") for (int nf_ = 0; nf_ < 2; ++nf_) {                     \
      const char* p_ =                                                        \
          smem + (bufc)*24576 + 16384 + (wc * 32 + nf_ * 16 + fr) * 128;      \
      bF[nf_][0] = *(const i32x4*)(p_ + csw0);                                \
      bF[nf_][1] = *(const i32x4*)(p_ + csw1);                                \
    }                                                                         \
    _Pragma("unroll") for (int mf_ = 0; mf_ < 4; ++mf_) {                     \
      const char* p_ = smem + (bufc)*24576 + (wr * 64 + mf_ * 16 + fr) * 128; \
      aF[mf_][0] = *(const i32x4*)(p_ + csw0);                                \
      aF[mf_][1] = *(const i32x4*)(p_ + csw1);                                \
    }                                                                         \
    asm volatile("s_waitcnt lgkmcnt(0)" ::: "memory");                        \
    __builtin_amdgcn_sched_barrier(0);                                        \
    __builtin_amdgcn_s_barrier(); /* all waves' reads of bufc done */         \
    STAGE_T(bufc, (T) + 2);       /* safe to overwrite bufc now */            \
    _Pragma("unroll") for (int nf_ = 0; nf_ < 2; ++nf_) {                     \
      sN[nf_] = scales[(size_t)(((T) + 1) & 31) * OUT_F + n0 + wc * 32 +      \
                       nf_ * 16 + fr];                                        \
    }                                                                         \
    __builtin_amdgcn_s_setprio(1);                                            \
    _Pragma("unroll") for (int nf_ = 0; nf_ < 2; ++nf_) {                     \
      i32x4 iacc[4];                                                          \
      _Pragma("unroll") for (int mf_ = 0; mf_ < 4; ++mf_) {                   \
        iacc[mf_] = __builtin_amdgcn_mfma_i32_16x16x64_i8(                    \
            aF[mf_][0], bF[nf_][0], zero4, 0, 0, 0);                          \
      }                                                                       \
      _Pragma("unroll") for (int mf_ = 0; mf_ < 4; ++mf_) {                   \
        iacc[mf_] = __builtin_amdgcn_mfma_i32_16x16x64_i8(                    \
            aF[mf_][1], bF[nf_][1], iacc[mf_], 0, 0, 0);                      \
      }                                                                       \
      _Pragma("unroll") for (int mf_ = 0; mf_ < 4; ++mf_)                     \
          _Pragma("unroll") for (int r_ = 0; r_ < 4; ++r_) {                  \
        facc[mf_][nf_][r_] += sC[nf_] * (float)iacc[mf_][r_];                 \
      }                                                                       \
    }                                                                         \
    __builtin_amdgcn_s_setprio(0);                                            \
    __builtin_amdgcn_sched_barrier(0);                                        \
    asm volatile("s_waitcnt vmcnt(8)" ::: "memory");                          \
    __builtin_amdgcn_s_barrier();                                             \
  } while (0)

__global__ __launch_bounds__(256, 3) void k_gemm_i8(
    const int8_t* __restrict__ xq,    // [TOKENS][IN_F]
    const int8_t* __restrict__ wq,    // [OUT_F][IN_F]
    const float* __restrict__ scales, // [32][OUT_F]
    const float* __restrict__ xs,     // [TOKENS]
    const float* __restrict__ bias,   // [OUT_F]
    float* __restrict__ out) {        // [TOKENS][OUT_F]
  extern __shared__ __align__(16) char smem[];  // 49152 B

  // XCD chunking: xcd owns bm range xcd*8..+7; bn sweeps fast.
  const int bidx = blockIdx.x;
  const int xcd = bidx & 7;
  const int slot = bidx >> 3;             // 0..511
  const int bm = xcd * 8 + (slot >> 6);   // 0..63
  const int bn = slot & 63;               // 0..63
  const int m0 = bm * 128;
  const int n0 = bn * 64;

  const int t = threadIdx.x;
  const int lane = t & 63;
  const int wid = t >> 6;    // 4 waves
  const int wr = wid >> 1;   // 2 (M)
  const int wc = wid & 1;    // 2 (N)
  const int fr = lane & 15;
  const int hq = lane >> 4;  // k-quarter (16 int8)

  const int csw0 = (hq ^ (fr & 7)) * 16;
  const int csw1 = ((hq ^ 4) ^ (fr & 7)) * 16;

  // staging constants: A 16KB = 16 instr (4/wave), B 8KB = 8 instr (2/wave)
  int goffA[4], ldsA[4], goffB[2], ldsB[2];
#pragma unroll
  for (int i = 0; i < 4; ++i) {
    const int srow = wid * 32 + i * 8 + (lane >> 3);  // 0..127
    const int sch = (lane & 7) ^ (srow & 7);          // inverse swizzle
    goffA[i] = srow * IN_F + sch * 16;
    ldsA[i] = (wid * 4 + i) * 1024;                   // wave-uniform
  }
#pragma unroll
  for (int i = 0; i < 2; ++i) {
    const int srow = wid * 16 + i * 8 + (lane >> 3);  // 0..63
    const int sch = (lane & 7) ^ (srow & 7);
    goffB[i] = srow * IN_F + sch * 16;
    ldsB[i] = 16384 + (wid * 2 + i) * 1024;
  }

  const char* Ag = (const char*)(xq + (size_t)m0 * IN_F);
  const char* Bg = (const char*)(wq + (size_t)n0 * IN_F);

  f32x4 facc[4][2];
#pragma unroll
  for (int i = 0; i < 4; ++i)
#pragma unroll
    for (int j = 0; j < 2; ++j) facc[i][j] = (f32x4){0.f, 0.f, 0.f, 0.f};
  const i32x4 zero4 = {0, 0, 0, 0};

  i32x4 aF[4][2];
  i32x4 bF[2][2];
  float sA[2], sB[2];

  // ---- prologue: stage tile0(buf0), scales(tile0)->sA, stage tile1(buf1);
  // drain tile0+sA (keep tile1's 6 in flight).
  STAGE_T(0, 0);
#pragma unroll
  for (int nf = 0; nf < 2; ++nf)
    sA[nf] = scales[(size_t)0 * OUT_F + n0 + wc * 32 + nf * 16 + fr];
  STAGE_T(1, 1);
  asm volatile("s_waitcnt vmcnt(6) lgkmcnt(0)" ::: "memory");
  __builtin_amdgcn_s_barrier();

  // ---- main loop: 32 tiles (= groups), bufs alternate, sA/sB ping-pong.
#pragma unroll 1
  for (int it = 0; it < 16; ++it) {
    const int T = 2 * it;
    PHASE(0, T, sA, sB);
    PHASE(1, T + 1, sB, sA);
  }

  // ---- epilogue: out = xs[m]*facc + bias[n]
  float bv[2];
#pragma unroll
  for (int nf = 0; nf < 2; ++nf) bv[nf] = bias[n0 + wc * 32 + nf * 16 + fr];
#pragma unroll
  for (int mf = 0; mf < 4; ++mf) {
#pragma unroll
    for (int r = 0; r < 4; ++r) {
      const int m = m0 + wr * 64 + mf * 16 + hq * 4 + r;
      const float xsv = xs[m];
      float* o = out + (size_t)m * OUT_F + n0;
#pragma unroll
      for (int nf = 0; nf < 2; ++nf) {
        o[wc * 32 + nf * 16 + fr] = xsv * facc[mf][nf][r] + bv[nf];
      }
    }
  }
}

// ---------------------------------------------------------------------------
extern "C" void kernel_launch(void* const* d_in, const int* in_sizes, int n_in,
                              void* d_out, int out_size, void* d_ws,
                              size_t ws_size, hipStream_t stream) {
  const float* x = (const float*)d_in[0];
  const int* qweight = (const int*)d_in[1];
  const int* qzeros = (const int*)d_in[2];
  const float* scales = (const float*)d_in[3];
  const float* bias = (const float*)d_in[4];
  float* out = (float*)d_out;

  int8_t* xq = (int8_t*)d_ws;                          // 32 MiB
  int8_t* wq = xq + (size_t)TOKENS * IN_F;             // +16 MiB
  float* xs = (float*)(wq + (size_t)OUT_F * IN_F);     // +32 KiB

  (void)hipFuncSetAttribute(reinterpret_cast<const void*>(&k_gemm_i8),
                            hipFuncAttributeMaxDynamicSharedMemorySize, 49152);

  k_quant_x<<<TOKENS, 256, 0, stream>>>(x, xq, xs);
  k_dequant_w8<<<1024, 256, 0, stream>>>(qweight, qzeros, wq);
  k_gemm_i8<<<(TOKENS / 128) * (OUT_F / 64), 256, 49152, stream>>>(
      xq, wq, scales, xs, bias, out);
}

// Round 13
// 259.029 us; speedup vs baseline: 3.1275x; 1.0695x over previous
//
#include <hip/hip_runtime.h>
#include <hip/hip_bf16.h>
#include <stdint.h>

#define TOKENS 8192
#define IN_F   4096
#define OUT_F  4096
#define GROUP  128

typedef __attribute__((ext_vector_type(4))) int   i32x4;
typedef __attribute__((ext_vector_type(4))) float f32x4;

// ---------------------------------------------------------------------------
// Kernel 1: quantize x rows to int8 with per-token scale. out = xs[m]*xq.
// ---------------------------------------------------------------------------
__global__ __launch_bounds__(256) void k_quant_x(const float* __restrict__ x,
                                                 int8_t* __restrict__ xq,
                                                 float* __restrict__ xs) {
  const int row = blockIdx.x;
  const int t = threadIdx.x;
  const float4* xr = (const float4*)(x + (size_t)row * IN_F) + t * 4;
  float f[16];
  *(float4*)&f[0] = xr[0];
  *(float4*)&f[4] = xr[1];
  *(float4*)&f[8] = xr[2];
  *(float4*)&f[12] = xr[3];
  float am = 0.f;
#pragma unroll
  for (int j = 0; j < 16; ++j) am = fmaxf(am, fabsf(f[j]));
#pragma unroll
  for (int off = 32; off; off >>= 1) am = fmaxf(am, __shfl_xor(am, off));
  __shared__ float red[4];
  if ((t & 63) == 0) red[t >> 6] = am;
  __syncthreads();
  am = fmaxf(fmaxf(red[0], red[1]), fmaxf(red[2], red[3]));
  am = fmaxf(am, 1e-8f);
  const float inv = 127.f / am;
  if (t == 0) xs[row] = am / 127.f;
  union {
    i32x4 v;
    int8_t c[16];
  } u;
#pragma unroll
  for (int j = 0; j < 16; ++j) u.c[j] = (int8_t)__float2int_rn(f[j] * inv);
  ((i32x4*)(xq + (size_t)row * IN_F))[t] = u.v;
}

// ---------------------------------------------------------------------------
// Kernel 2: unpack weights -> W'^T int8 [OUT_F][IN_F], w' = w - z (exact).
// ---------------------------------------------------------------------------
__global__ __launch_bounds__(256) void k_dequant_w8(
    const int* __restrict__ qweight, const int* __restrict__ qzeros,
    int8_t* __restrict__ wq) {
  __shared__ __align__(16) int8_t sW[256][80];  // [n][k 64 + 16 pad]
  const int nt = blockIdx.x & 15;   // 16 n-tiles
  const int kt = blockIdx.x >> 4;   // 64 k-tiles
  const int n0 = nt * 256;
  const int k0 = kt * 64;
  const int g = k0 / GROUP;
  const int t = threadIdx.x;
  const int n = n0 + t;

  const unsigned zw =
      ((const unsigned*)qzeros)[(size_t)g * (OUT_F / 8) + (n >> 3)];
  const int z = (int)((zw >> ((n & 7) * 4)) & 15u);
  const int kw0 = k0 >> 3;
#pragma unroll
  for (int kw = 0; kw < 8; ++kw) {
    const unsigned w = ((const unsigned*)qweight)[(size_t)(kw0 + kw) * OUT_F + n];
#pragma unroll
    for (int j = 0; j < 8; ++j) {
      const int q = (int)((w >> (4 * j)) & 15u);
      sW[t][kw * 8 + j] = (int8_t)(q - z);
    }
  }
  __syncthreads();
#pragma unroll
  for (int pass = 0; pass < 4; ++pass) {
    const int row = pass * 64 + (t >> 2);
    const int kc = t & 3;
    i32x4 v = *(const i32x4*)&sW[row][kc * 16];
    *(i32x4*)(wq + (size_t)(n0 + row) * IN_F + k0 + kc * 16) = v;
  }
}

// ---------------------------------------------------------------------------
// Kernel 3: int8 MFMA GEMM, block 128x64, 4 waves (2M x 2N), wave 64x32.
// LDS = 2 bufs x (A 16K + B 8K) = 48 KB -> 3 blocks/CU; launch_bounds
// (256,3) -> ~170-reg cap (measured 84 VGPR, no spill). Round-13 change:
// XCD map TRANSPOSED — each XCD OWNS an 8-bn (512-col, 2 MB) B-slice,
// L2-resident for the whole kernel; bm streams (co-resident same-bm
// blocks share each 0.5 MB A-panel via L2). Round-12's map swept all
// 16 MB of B per XCD round -> 558 MB FETCH, L3-latency stage stalls.
// Schedule per phase (round-11's proven WAR invariant):
//   reads -> lgkm(0) -> barrier -> STAGE T+2 (same buf) -> scale-prefetch
//   -> MFMA+DEQ -> vmcnt(8) -> barrier
// ---------------------------------------------------------------------------
__device__ inline void gload_lds16(const void* g, void* l) {
  __builtin_amdgcn_global_load_lds(
      (const __attribute__((address_space(1))) void*)g,
      (__attribute__((address_space(3))) void*)l, 16, 0, 0);
}

// stage tile (A 4 + B 2 gloads per wave) into buf
#define STAGE_T(buf, tile)                                                    \
  do {                                                                        \
    _Pragma("unroll") for (int i_ = 0; i_ < 4; ++i_) {                        \
      gload_lds16(Ag + goffA[i_] + (size_t)((tile) & 31) * 128,               \
                  smem + (buf)*24576 + ldsA[i_]);                             \
    }                                                                         \
    _Pragma("unroll") for (int i_ = 0; i_ < 2; ++i_) {                        \
      gload_lds16(Bg + goffB[i_] + (size_t)((tile) & 31) * 128,               \
                  smem + (buf)*24576 + ldsB[i_]);                             \
    }                                                                         \
  } while (0)

// one K=128 tile (= one quant group); sC: scales for T (ready),
// sN: loads scales for T+1 (consumed next phase).
#define PHASE(bufc, T, sC, sN)                                                \
  do {                                                                        \
    _Pragma("unroll") for (int nf_ = 0; nf_ < 2; ++nf_) {                     \
      const char* p_ =                                                        \
          smem + (bufc)*24576 + 16384 + (wc * 32 + nf_ * 16 + fr) * 128;      \
      bF[nf_][0] = *(const i32x4*)(p_ + csw0);                                \
      bF[nf_][1] = *(const i32x4*)(p_ + csw1);                                \
    }                                                                         \
    _Pragma("unroll") for (int mf_ = 0; mf_ < 4; ++mf_) {                     \
      const char* p_ = smem + (bufc)*24576 + (wr * 64 + mf_ * 16 + fr) * 128; \
      aF[mf_][0] = *(const i32x4*)(p_ + csw0);                                \
      aF[mf_][1] = *(const i32x4*)(p_ + csw1);                                \
    }                                                                         \
    asm volatile("s_waitcnt lgkmcnt(0)" ::: "memory");                        \
    __builtin_amdgcn_sched_barrier(0);                                        \
    __builtin_amdgcn_s_barrier(); /* all waves' reads of bufc done */         \
    STAGE_T(bufc, (T) + 2);       /* safe to overwrite bufc now */            \
    _Pragma("unroll") for (int nf_ = 0; nf_ < 2; ++nf_) {                     \
      sN[nf_] = scales[(size_t)(((T) + 1) & 31) * OUT_F + n0 + wc * 32 +      \
                       nf_ * 16 + fr];                                        \
    }                                                                         \
    __builtin_amdgcn_s_setprio(1);                                            \
    _Pragma("unroll") for (int nf_ = 0; nf_ < 2; ++nf_) {                     \
      i32x4 iacc[4];                                                          \
      _Pragma("unroll") for (int mf_ = 0; mf_ < 4; ++mf_) {                   \
        iacc[mf_] = __builtin_amdgcn_mfma_i32_16x16x64_i8(                    \
            aF[mf_][0], bF[nf_][0], zero4, 0, 0, 0);                          \
      }                                                                       \
      _Pragma("unroll") for (int mf_ = 0; mf_ < 4; ++mf_) {                   \
        iacc[mf_] = __builtin_amdgcn_mfma_i32_16x16x64_i8(                    \
            aF[mf_][1], bF[nf_][1], iacc[mf_], 0, 0, 0);                      \
      }                                                                       \
      _Pragma("unroll") for (int mf_ = 0; mf_ < 4; ++mf_)                     \
          _Pragma("unroll") for (int r_ = 0; r_ < 4; ++r_) {                  \
        facc[mf_][nf_][r_] += sC[nf_] * (float)iacc[mf_][r_];                 \
      }                                                                       \
    }                                                                         \
    __builtin_amdgcn_s_setprio(0);                                            \
    __builtin_amdgcn_sched_barrier(0);                                        \
    asm volatile("s_waitcnt vmcnt(8)" ::: "memory");                          \
    __builtin_amdgcn_s_barrier();                                             \
  } while (0)

__global__ __launch_bounds__(256, 3) void k_gemm_i8(
    const int8_t* __restrict__ xq,    // [TOKENS][IN_F]
    const int8_t* __restrict__ wq,    // [OUT_F][IN_F]
    const float* __restrict__ scales, // [32][OUT_F]
    const float* __restrict__ xs,     // [TOKENS]
    const float* __restrict__ bias,   // [OUT_F]
    float* __restrict__ out) {        // [TOKENS][OUT_F]
  extern __shared__ __align__(16) char smem[];  // 49152 B

  // XCD chunking (round-13): xcd OWNS bn range xcd*8..+7 (2 MB B-slice,
  // L2-resident all kernel); bm sweeps slowly; same-bm blocks co-resident
  // share the A-panel.
  const int bidx = blockIdx.x;
  const int xcd = bidx & 7;
  const int slot = bidx >> 3;             // 0..511
  const int bm = slot >> 3;               // 0..63
  const int bn = xcd * 8 + (slot & 7);    // 0..63
  const int m0 = bm * 128;
  const int n0 = bn * 64;

  const int t = threadIdx.x;
  const int lane = t & 63;
  const int wid = t >> 6;    // 4 waves
  const int wr = wid >> 1;   // 2 (M)
  const int wc = wid & 1;    // 2 (N)
  const int fr = lane & 15;
  const int hq = lane >> 4;  // k-quarter (16 int8)

  const int csw0 = (hq ^ (fr & 7)) * 16;
  const int csw1 = ((hq ^ 4) ^ (fr & 7)) * 16;

  // staging constants: A 16KB = 16 instr (4/wave), B 8KB = 8 instr (2/wave)
  int goffA[4], ldsA[4], goffB[2], ldsB[2];
#pragma unroll
  for (int i = 0; i < 4; ++i) {
    const int srow = wid * 32 + i * 8 + (lane >> 3);  // 0..127
    const int sch = (lane & 7) ^ (srow & 7);          // inverse swizzle
    goffA[i] = srow * IN_F + sch * 16;
    ldsA[i] = (wid * 4 + i) * 1024;                   // wave-uniform
  }
#pragma unroll
  for (int i = 0; i < 2; ++i) {
    const int srow = wid * 16 + i * 8 + (lane >> 3);  // 0..63
    const int sch = (lane & 7) ^ (srow & 7);
    goffB[i] = srow * IN_F + sch * 16;
    ldsB[i] = 16384 + (wid * 2 + i) * 1024;
  }

  const char* Ag = (const char*)(xq + (size_t)m0 * IN_F);
  const char* Bg = (const char*)(wq + (size_t)n0 * IN_F);

  f32x4 facc[4][2];
#pragma unroll
  for (int i = 0; i < 4; ++i)
#pragma unroll
    for (int j = 0; j < 2; ++j) facc[i][j] = (f32x4){0.f, 0.f, 0.f, 0.f};
  const i32x4 zero4 = {0, 0, 0, 0};

  i32x4 aF[4][2];
  i32x4 bF[2][2];
  float sA[2], sB[2];

  // ---- prologue: stage tile0(buf0), scales(tile0)->sA, stage tile1(buf1);
  // drain tile0+sA (keep tile1's 6 in flight).
  STAGE_T(0, 0);
#pragma unroll
  for (int nf = 0; nf < 2; ++nf)
    sA[nf] = scales[(size_t)0 * OUT_F + n0 + wc * 32 + nf * 16 + fr];
  STAGE_T(1, 1);
  asm volatile("s_waitcnt vmcnt(6) lgkmcnt(0)" ::: "memory");
  __builtin_amdgcn_s_barrier();

  // ---- main loop: 32 tiles (= groups), bufs alternate, sA/sB ping-pong.
#pragma unroll 1
  for (int it = 0; it < 16; ++it) {
    const int T = 2 * it;
    PHASE(0, T, sA, sB);
    PHASE(1, T + 1, sB, sA);
  }

  // ---- epilogue: out = xs[m]*facc + bias[n]
  float bv[2];
#pragma unroll
  for (int nf = 0; nf < 2; ++nf) bv[nf] = bias[n0 + wc * 32 + nf * 16 + fr];
#pragma unroll
  for (int mf = 0; mf < 4; ++mf) {
#pragma unroll
    for (int r = 0; r < 4; ++r) {
      const int m = m0 + wr * 64 + mf * 16 + hq * 4 + r;
      const float xsv = xs[m];
      float* o = out + (size_t)m * OUT_F + n0;
#pragma unroll
      for (int nf = 0; nf < 2; ++nf) {
        o[wc * 32 + nf * 16 + fr] = xsv * facc[mf][nf][r] + bv[nf];
      }
    }
  }
}

// ---------------------------------------------------------------------------
extern "C" void kernel_launch(void* const* d_in, const int* in_sizes, int n_in,
                              void* d_out, int out_size, void* d_ws,
                              size_t ws_size, hipStream_t stream) {
  const float* x = (const float*)d_in[0];
  const int* qweight = (const int*)d_in[1];
  const int* qzeros = (const int*)d_in[2];
  const float* scales = (const float*)d_in[3];
  const float* bias = (const float*)d_in[4];
  float* out = (float*)d_out;

  int8_t* xq = (int8_t*)d_ws;                          // 32 MiB
  int8_t* wq = xq + (size_t)TOKENS * IN_F;             // +16 MiB
  float* xs = (float*)(wq + (size_t)OUT_F * IN_F);     // +32 KiB

  (void)hipFuncSetAttribute(reinterpret_cast<const void*>(&k_gemm_i8),
                            hipFuncAttributeMaxDynamicSharedMemorySize, 49152);

  k_quant_x<<<TOKENS, 256, 0, stream>>>(x, xq, xs);
  k_dequant_w8<<<1024, 256, 0, stream>>>(qweight, qzeros, wq);
  k_gemm_i8<<<(TOKENS / 128) * (OUT_F / 64), 256, 49152, stream>>>(
      xq, wq, scales, xs, bias, out);
}

// Round 14
// 216.218 us; speedup vs baseline: 3.7467x; 1.1980x over previous
//
#include <hip/hip_runtime.h>
#include <hip/hip_bf16.h>
#include <stdint.h>

#define TOKENS 8192
#define IN_F   4096
#define OUT_F  4096
#define GROUP  128

typedef __attribute__((ext_vector_type(4))) int   i32x4;
typedef __attribute__((ext_vector_type(4))) float f32x4;

// ---------------------------------------------------------------------------
// Kernel 1: quantize x rows to int8 with per-token scale. x ~ xs[m]*xq.
// ---------------------------------------------------------------------------
__global__ __launch_bounds__(256) void k_quant_x(const float* __restrict__ x,
                                                 int8_t* __restrict__ xq,
                                                 float* __restrict__ xs) {
  const int row = blockIdx.x;
  const int t = threadIdx.x;
  const float4* xr = (const float4*)(x + (size_t)row * IN_F) + t * 4;
  float f[16];
  *(float4*)&f[0] = xr[0];
  *(float4*)&f[4] = xr[1];
  *(float4*)&f[8] = xr[2];
  *(float4*)&f[12] = xr[3];
  float am = 0.f;
#pragma unroll
  for (int j = 0; j < 16; ++j) am = fmaxf(am, fabsf(f[j]));
#pragma unroll
  for (int off = 32; off; off >>= 1) am = fmaxf(am, __shfl_xor(am, off));
  __shared__ float red[4];
  if ((t & 63) == 0) red[t >> 6] = am;
  __syncthreads();
  am = fmaxf(fmaxf(red[0], red[1]), fmaxf(red[2], red[3]));
  am = fmaxf(am, 1e-8f);
  const float inv = 127.f / am;
  if (t == 0) xs[row] = am / 127.f;
  union {
    i32x4 v;
    int8_t c[16];
  } u;
#pragma unroll
  for (int j = 0; j < 16; ++j) u.c[j] = (int8_t)__float2int_rn(f[j] * inv);
  ((i32x4*)(xq + (size_t)row * IN_F))[t] = u.v;
}

// ---------------------------------------------------------------------------
// Kernel 2 (round-14): REQUANTIZE weights to int8 with ONE scale per column:
//   Sw[n] = max_g s_g[n]*max(z_g, 15-z_g) / 127   (provable bound, no clip)
//   wq[n][k] = round( s_g*(w-z_g) / Sw[n] )  in [-127,127]
// GEMM then needs NO per-group dequant; scales applied in epilogue.
// Block: 16 cols x 16 k-segments (2 groups each), 256 blocks.
// ---------------------------------------------------------------------------
__global__ __launch_bounds__(256) void k_requant_w8(
    const int* __restrict__ qweight, const int* __restrict__ qzeros,
    const float* __restrict__ scales, int8_t* __restrict__ wq,
    float* __restrict__ sw) {
  __shared__ float smax[16][17];
  const int n0 = blockIdx.x * 16;
  const int col = threadIdx.x & 15;
  const int seg = threadIdx.x >> 4;  // 0..15, 2 groups each
  const int n = n0 + col;

  int zloc[2];
  float sloc[2];
  float m = 0.f;
#pragma unroll
  for (int i = 0; i < 2; ++i) {
    const int g = seg * 2 + i;
    const unsigned zw =
        ((const unsigned*)qzeros)[(size_t)g * (OUT_F / 8) + (n >> 3)];
    const int z = (int)((zw >> ((n & 7) * 4)) & 15u);
    const float s = scales[(size_t)g * OUT_F + n];
    zloc[i] = z;
    sloc[i] = s;
    m = fmaxf(m, s * (float)(z > 15 - z ? z : 15 - z));
  }
  // reduce max over 16 segs (tree via LDS: write, then seg<... simple 2-step)
  smax[col][seg] = m;
  __syncthreads();
  float Sw = 0.f;
#pragma unroll
  for (int ss = 0; ss < 16; ++ss) Sw = fmaxf(Sw, smax[col][ss]);
  Sw /= 127.f;  // > 0 always (s >= 0.001, max(z,15-z) >= 8)
  if (seg == 0) sw[n] = Sw;
  const float inv = 1.f / Sw;

#pragma unroll
  for (int i = 0; i < 2; ++i) {
    const int g = seg * 2 + i;
    const int z = zloc[i];
    const float f = sloc[i] * inv;  // int8 units per nibble-delta
#pragma unroll
    for (int kw = 0; kw < 16; ++kw) {
      const unsigned w =
          ((const unsigned*)qweight)[(size_t)(g * 16 + kw) * OUT_F + n];
      unsigned lo = 0, hi = 0;
#pragma unroll
      for (int j = 0; j < 8; ++j) {
        const int q = (int)((w >> (4 * j)) & 15u);
        const int v = __float2int_rn(f * (float)(q - z));  // |v| <= 127
        const unsigned b = (unsigned)(v & 255);
        if (j < 4)
          lo |= b << (8 * j);
        else
          hi |= b << (8 * (j - 4));
      }
      uint2 pk = {lo, hi};
      *(uint2*)(wq + (size_t)n * IN_F + (size_t)(g * 16 + kw) * 8) = pk;
    }
  }
}

// ---------------------------------------------------------------------------
// Kernel 3: PURE int8 MFMA GEMM (no in-loop dequant). Block 128x64,
// 4 waves (2M x 2N), wave 64x32. LDS = 2 bufs x 24KB = 48 KB -> 3 blocks/CU;
// __launch_bounds__(256,3). int32 acc over full K (max 6.6e7, no overflow).
// Per phase: reads -> lgkm(0) -> barrier -> STAGE T+2 (same buf; round-11
// WAR invariant) -> 16 MFMA (accumulating) -> vmcnt(6) -> barrier.
// XCD map: xcd owns 8-bn (2 MB) B-slice, L2-resident; bm streams.
// Epilogue: out = xs[m]*Sw[n]*acc + bias[n].
// ---------------------------------------------------------------------------
__device__ inline void gload_lds16(const void* g, void* l) {
  __builtin_amdgcn_global_load_lds(
      (const __attribute__((address_space(1))) void*)g,
      (__attribute__((address_space(3))) void*)l, 16, 0, 0);
}

#define STAGE_T(buf, tile)                                                    \
  do {                                                                        \
    _Pragma("unroll") for (int i_ = 0; i_ < 4; ++i_) {                        \
      gload_lds16(Ag + goffA[i_] + (size_t)((tile) & 31) * 128,               \
                  smem + (buf)*24576 + ldsA[i_]);                             \
    }                                                                         \
    _Pragma("unroll") for (int i_ = 0; i_ < 2; ++i_) {                        \
      gload_lds16(Bg + goffB[i_] + (size_t)((tile) & 31) * 128,               \
                  smem + (buf)*24576 + ldsB[i_]);                             \
    }                                                                         \
  } while (0)

#define PHASE(bufc, T)                                                        \
  do {                                                                        \
    _Pragma("unroll") for (int nf_ = 0; nf_ < 2; ++nf_) {                     \
      const char* p_ =                                                        \
          smem + (bufc)*24576 + 16384 + (wc * 32 + nf_ * 16 + fr) * 128;      \
      bF[nf_][0] = *(const i32x4*)(p_ + csw0);                                \
      bF[nf_][1] = *(const i32x4*)(p_ + csw1);                                \
    }                                                                         \
    _Pragma("unroll") for (int mf_ = 0; mf_ < 4; ++mf_) {                     \
      const char* p_ = smem + (bufc)*24576 + (wr * 64 + mf_ * 16 + fr) * 128; \
      aF[mf_][0] = *(const i32x4*)(p_ + csw0);                                \
      aF[mf_][1] = *(const i32x4*)(p_ + csw1);                                \
    }                                                                         \
    asm volatile("s_waitcnt lgkmcnt(0)" ::: "memory");                        \
    __builtin_amdgcn_sched_barrier(0);                                        \
    __builtin_amdgcn_s_barrier(); /* all waves' reads of bufc done */         \
    STAGE_T(bufc, (T) + 2);       /* safe to overwrite bufc now */            \
    __builtin_amdgcn_s_setprio(1);                                            \
    _Pragma("unroll") for (int nf_ = 0; nf_ < 2; ++nf_)                       \
        _Pragma("unroll") for (int mf_ = 0; mf_ < 4; ++mf_) {                 \
      iacc[mf_][nf_] = __builtin_amdgcn_mfma_i32_16x16x64_i8(                 \
          aF[mf_][0], bF[nf_][0], iacc[mf_][nf_], 0, 0, 0);                   \
    }                                                                         \
    _Pragma("unroll") for (int nf_ = 0; nf_ < 2; ++nf_)                       \
        _Pragma("unroll") for (int mf_ = 0; mf_ < 4; ++mf_) {                 \
      iacc[mf_][nf_] = __builtin_amdgcn_mfma_i32_16x16x64_i8(                 \
          aF[mf_][1], bF[nf_][1], iacc[mf_][nf_], 0, 0, 0);                   \
    }                                                                         \
    __builtin_amdgcn_s_setprio(0);                                            \
    __builtin_amdgcn_sched_barrier(0);                                        \
    asm volatile("s_waitcnt vmcnt(6)" ::: "memory");                          \
    __builtin_amdgcn_s_barrier();                                             \
  } while (0)

__global__ __launch_bounds__(256, 3) void k_gemm_i8(
    const int8_t* __restrict__ xq,   // [TOKENS][IN_F]
    const int8_t* __restrict__ wq,   // [OUT_F][IN_F]
    const float* __restrict__ sw,    // [OUT_F]
    const float* __restrict__ xs,    // [TOKENS]
    const float* __restrict__ bias,  // [OUT_F]
    float* __restrict__ out) {       // [TOKENS][OUT_F]
  extern __shared__ __align__(16) char smem[];  // 49152 B

  // XCD map: xcd OWNS bn range xcd*8..+7 (2 MB B-slice); bm sweeps slowly.
  const int bidx = blockIdx.x;
  const int xcd = bidx & 7;
  const int slot = bidx >> 3;           // 0..511
  const int bm = slot >> 3;             // 0..63
  const int bn = xcd * 8 + (slot & 7);  // 0..63
  const int m0 = bm * 128;
  const int n0 = bn * 64;

  const int t = threadIdx.x;
  const int lane = t & 63;
  const int wid = t >> 6;    // 4 waves
  const int wr = wid >> 1;   // 2 (M)
  const int wc = wid & 1;    // 2 (N)
  const int fr = lane & 15;
  const int hq = lane >> 4;  // k-quarter (16 int8)

  const int csw0 = (hq ^ (fr & 7)) * 16;
  const int csw1 = ((hq ^ 4) ^ (fr & 7)) * 16;

  int goffA[4], ldsA[4], goffB[2], ldsB[2];
#pragma unroll
  for (int i = 0; i < 4; ++i) {
    const int srow = wid * 32 + i * 8 + (lane >> 3);  // 0..127
    const int sch = (lane & 7) ^ (srow & 7);          // inverse swizzle
    goffA[i] = srow * IN_F + sch * 16;
    ldsA[i] = (wid * 4 + i) * 1024;
  }
#pragma unroll
  for (int i = 0; i < 2; ++i) {
    const int srow = wid * 16 + i * 8 + (lane >> 3);  // 0..63
    const int sch = (lane & 7) ^ (srow & 7);
    goffB[i] = srow * IN_F + sch * 16;
    ldsB[i] = 16384 + (wid * 2 + i) * 1024;
  }

  const char* Ag = (const char*)(xq + (size_t)m0 * IN_F);
  const char* Bg = (const char*)(wq + (size_t)n0 * IN_F);

  i32x4 iacc[4][2];
#pragma unroll
  for (int i = 0; i < 4; ++i)
#pragma unroll
    for (int j = 0; j < 2; ++j) iacc[i][j] = (i32x4){0, 0, 0, 0};

  i32x4 aF[4][2];
  i32x4 bF[2][2];

  // ---- prologue: stage tiles 0 (buf0), 1 (buf1); drain tile0.
  STAGE_T(0, 0);
  STAGE_T(1, 1);
  asm volatile("s_waitcnt vmcnt(6) lgkmcnt(0)" ::: "memory");
  __builtin_amdgcn_s_barrier();

  // ---- main loop: 32 K-tiles, bufs alternate.
#pragma unroll 1
  for (int it = 0; it < 16; ++it) {
    const int T = 2 * it;
    PHASE(0, T);
    PHASE(1, T + 1);
  }

  // ---- epilogue: out = xs[m]*Sw[n]*acc + bias[n]
  float swv[2], bv[2];
#pragma unroll
  for (int nf = 0; nf < 2; ++nf) {
    const int n = n0 + wc * 32 + nf * 16 + fr;
    swv[nf] = sw[n];
    bv[nf] = bias[n];
  }
#pragma unroll
  for (int mf = 0; mf < 4; ++mf) {
#pragma unroll
    for (int r = 0; r < 4; ++r) {
      const int m = m0 + wr * 64 + mf * 16 + hq * 4 + r;
      const float xsv = xs[m];
      float* o = out + (size_t)m * OUT_F + n0;
#pragma unroll
      for (int nf = 0; nf < 2; ++nf) {
        o[wc * 32 + nf * 16 + fr] =
            xsv * swv[nf] * (float)iacc[mf][nf][r] + bv[nf];
      }
    }
  }
}

// ---------------------------------------------------------------------------
extern "C" void kernel_launch(void* const* d_in, const int* in_sizes, int n_in,
                              void* d_out, int out_size, void* d_ws,
                              size_t ws_size, hipStream_t stream) {
  const float* x = (const float*)d_in[0];
  const int* qweight = (const int*)d_in[1];
  const int* qzeros = (const int*)d_in[2];
  const float* scales = (const float*)d_in[3];
  const float* bias = (const float*)d_in[4];
  float* out = (float*)d_out;

  int8_t* xq = (int8_t*)d_ws;                       // 32 MiB
  int8_t* wq = xq + (size_t)TOKENS * IN_F;          // +16 MiB
  float* xs = (float*)(wq + (size_t)OUT_F * IN_F);  // +32 KiB
  float* sw = xs + TOKENS;                          // +16 KiB

  (void)hipFuncSetAttribute(reinterpret_cast<const void*>(&k_gemm_i8),
                            hipFuncAttributeMaxDynamicSharedMemorySize, 49152);

  k_quant_x<<<TOKENS, 256, 0, stream>>>(x, xq, xs);
  k_requant_w8<<<OUT_F / 16, 256, 0, stream>>>(qweight, qzeros, scales, wq, sw);
  k_gemm_i8<<<(TOKENS / 128) * (OUT_F / 64), 256, 49152, stream>>>(
      xq, wq, sw, xs, bias, out);
}

// Round 15
// 183.419 us; speedup vs baseline: 4.4167x; 1.1788x over previous
//
#include <hip/hip_runtime.h>
#include <hip/hip_bf16.h>
#include <stdint.h>

#define TOKENS 8192
#define IN_F   4096
#define OUT_F  4096
#define GROUP  128

typedef __attribute__((ext_vector_type(4))) int   i32x4;
typedef __attribute__((ext_vector_type(4))) float f32x4;

// ---------------------------------------------------------------------------
// Kernel 1: quantize x rows to int8 with per-token scale. x ~ xs[m]*xq.
// ---------------------------------------------------------------------------
__global__ __launch_bounds__(256) void k_quant_x(const float* __restrict__ x,
                                                 int8_t* __restrict__ xq,
                                                 float* __restrict__ xs) {
  const int row = blockIdx.x;
  const int t = threadIdx.x;
  const float4* xr = (const float4*)(x + (size_t)row * IN_F) + t * 4;
  float f[16];
  *(float4*)&f[0] = xr[0];
  *(float4*)&f[4] = xr[1];
  *(float4*)&f[8] = xr[2];
  *(float4*)&f[12] = xr[3];
  float am = 0.f;
#pragma unroll
  for (int j = 0; j < 16; ++j) am = fmaxf(am, fabsf(f[j]));
#pragma unroll
  for (int off = 32; off; off >>= 1) am = fmaxf(am, __shfl_xor(am, off));
  __shared__ float red[4];
  if ((t & 63) == 0) red[t >> 6] = am;
  __syncthreads();
  am = fmaxf(fmaxf(red[0], red[1]), fmaxf(red[2], red[3]));
  am = fmaxf(am, 1e-8f);
  const float inv = 127.f / am;
  if (t == 0) xs[row] = am / 127.f;
  union {
    i32x4 v;
    int8_t c[16];
  } u;
#pragma unroll
  for (int j = 0; j < 16; ++j) u.c[j] = (int8_t)__float2int_rn(f[j] * inv);
  ((i32x4*)(xq + (size_t)row * IN_F))[t] = u.v;
}

// ---------------------------------------------------------------------------
// Kernel 2: REQUANTIZE weights to int8 with ONE scale per column:
//   Sw[n] = max_g s_g[n]*max(z_g, 15-z_g) / 127   (provable bound, no clip)
//   wq[n][k] = round( s_g*(w-z_g) / Sw[n] )  in [-127,127]
// ---------------------------------------------------------------------------
__global__ __launch_bounds__(256) void k_requant_w8(
    const int* __restrict__ qweight, const int* __restrict__ qzeros,
    const float* __restrict__ scales, int8_t* __restrict__ wq,
    float* __restrict__ sw) {
  __shared__ float smax[16][17];
  const int n0 = blockIdx.x * 16;
  const int col = threadIdx.x & 15;
  const int seg = threadIdx.x >> 4;  // 0..15, 2 groups each
  const int n = n0 + col;

  int zloc[2];
  float sloc[2];
  float m = 0.f;
#pragma unroll
  for (int i = 0; i < 2; ++i) {
    const int g = seg * 2 + i;
    const unsigned zw =
        ((const unsigned*)qzeros)[(size_t)g * (OUT_F / 8) + (n >> 3)];
    const int z = (int)((zw >> ((n & 7) * 4)) & 15u);
    const float s = scales[(size_t)g * OUT_F + n];
    zloc[i] = z;
    sloc[i] = s;
    m = fmaxf(m, s * (float)(z > 15 - z ? z : 15 - z));
  }
  smax[col][seg] = m;
  __syncthreads();
  float Sw = 0.f;
#pragma unroll
  for (int ss = 0; ss < 16; ++ss) Sw = fmaxf(Sw, smax[col][ss]);
  Sw /= 127.f;  // > 0 always
  if (seg == 0) sw[n] = Sw;
  const float inv = 1.f / Sw;

#pragma unroll
  for (int i = 0; i < 2; ++i) {
    const int g = seg * 2 + i;
    const int z = zloc[i];
    const float f = sloc[i] * inv;
#pragma unroll
    for (int kw = 0; kw < 16; ++kw) {
      const unsigned w =
          ((const unsigned*)qweight)[(size_t)(g * 16 + kw) * OUT_F + n];
      unsigned lo = 0, hi = 0;
#pragma unroll
      for (int j = 0; j < 8; ++j) {
        const int q = (int)((w >> (4 * j)) & 15u);
        const int v = __float2int_rn(f * (float)(q - z));
        const unsigned b = (unsigned)(v & 255);
        if (j < 4)
          lo |= b << (8 * j);
        else
          hi |= b << (8 * (j - 4));
      }
      uint2 pk = {lo, hi};
      *(uint2*)(wq + (size_t)n * IN_F + (size_t)(g * 16 + kw) * 8) = pk;
    }
  }
}

// ---------------------------------------------------------------------------
// Kernel 3: PURE int8 MFMA GEMM. Round-15: block 128x128, 4 waves (2x2),
// wave tile 64x64 -> 32 MFMA per phase from 16 b128 reads (8 B/lane/MFMA,
// -33% LDS-read per MFMA vs 64x32) and 2x per-phase MFMA density.
// LDS = 2 bufs x (A16K + B16K) = 64 KB -> 2 blocks/CU. launch_bounds(256,2).
// Per phase (round-11 WAR invariant): 16 ds_reads -> lgkm(0) -> barrier ->
// STAGE T+2 (same buf) -> 32 MFMA -> vmcnt(8) -> barrier.
// vmcnt(8) keeps own 8 stage loads, drains T+1 for next phase.
// XCD map: xcd owns 4 bn (512 cols, 2 MB B-slice, L2-resident); bm streams.
// Epilogue: out = xs[m]*Sw[n]*acc + bias[n].
// ---------------------------------------------------------------------------
__device__ inline void gload_lds16(const void* g, void* l) {
  __builtin_amdgcn_global_load_lds(
      (const __attribute__((address_space(1))) void*)g,
      (__attribute__((address_space(3))) void*)l, 16, 0, 0);
}

#define STAGE_T(buf, tile)                                                    \
  do {                                                                        \
    _Pragma("unroll") for (int i_ = 0; i_ < 4; ++i_) {                        \
      gload_lds16(Ag + goffS[i_] + (size_t)((tile) & 31) * 128,               \
                  smem + (buf)*32768 + ldsS[i_]);                             \
    }                                                                         \
    _Pragma("unroll") for (int i_ = 0; i_ < 4; ++i_) {                        \
      gload_lds16(Bg + goffS[i_] + (size_t)((tile) & 31) * 128,               \
                  smem + (buf)*32768 + 16384 + ldsS[i_]);                     \
    }                                                                         \
  } while (0)

#define PHASE(bufc, T)                                                        \
  do {                                                                        \
    _Pragma("unroll") for (int nf_ = 0; nf_ < 4; ++nf_) {                     \
      const char* p_ =                                                        \
          smem + (bufc)*32768 + 16384 + (wc * 64 + nf_ * 16 + fr) * 128;      \
      bF[nf_][0] = *(const i32x4*)(p_ + csw0);                                \
      bF[nf_][1] = *(const i32x4*)(p_ + csw1);                                \
    }                                                                         \
    _Pragma("unroll") for (int mf_ = 0; mf_ < 4; ++mf_) {                     \
      const char* p_ = smem + (bufc)*32768 + (wr * 64 + mf_ * 16 + fr) * 128; \
      aF[mf_][0] = *(const i32x4*)(p_ + csw0);                                \
      aF[mf_][1] = *(const i32x4*)(p_ + csw1);                                \
    }                                                                         \
    asm volatile("s_waitcnt lgkmcnt(0)" ::: "memory");                        \
    __builtin_amdgcn_sched_barrier(0);                                        \
    __builtin_amdgcn_s_barrier(); /* all waves' reads of bufc done */         \
    STAGE_T(bufc, (T) + 2);       /* safe to overwrite bufc now */            \
    __builtin_amdgcn_s_setprio(1);                                            \
    _Pragma("unroll") for (int nf_ = 0; nf_ < 4; ++nf_)                       \
        _Pragma("unroll") for (int mf_ = 0; mf_ < 4; ++mf_) {                 \
      iacc[mf_][nf_] = __builtin_amdgcn_mfma_i32_16x16x64_i8(                 \
          aF[mf_][0], bF[nf_][0], iacc[mf_][nf_], 0, 0, 0);                   \
    }                                                                         \
    _Pragma("unroll") for (int nf_ = 0; nf_ < 4; ++nf_)                       \
        _Pragma("unroll") for (int mf_ = 0; mf_ < 4; ++mf_) {                 \
      iacc[mf_][nf_] = __builtin_amdgcn_mfma_i32_16x16x64_i8(                 \
          aF[mf_][1], bF[nf_][1], iacc[mf_][nf_], 0, 0, 0);                   \
    }                                                                         \
    __builtin_amdgcn_s_setprio(0);                                            \
    __builtin_amdgcn_sched_barrier(0);                                        \
    asm volatile("s_waitcnt vmcnt(8)" ::: "memory");                          \
    __builtin_amdgcn_s_barrier();                                             \
  } while (0)

__global__ __launch_bounds__(256, 2) void k_gemm_i8(
    const int8_t* __restrict__ xq,   // [TOKENS][IN_F]
    const int8_t* __restrict__ wq,   // [OUT_F][IN_F]
    const float* __restrict__ sw,    // [OUT_F]
    const float* __restrict__ xs,    // [TOKENS]
    const float* __restrict__ bias,  // [OUT_F]
    float* __restrict__ out) {       // [TOKENS][OUT_F]
  extern __shared__ __align__(16) char smem[];  // 65536 B

  // XCD map: xcd OWNS bn range xcd*4..+3 (512 cols, 2 MB B-slice);
  // bm sweeps slowly (4 consecutive slots share each A-panel via L2).
  const int bidx = blockIdx.x;
  const int xcd = bidx & 7;
  const int slot = bidx >> 3;           // 0..255
  const int bm = slot >> 2;             // 0..63
  const int bn = xcd * 4 + (slot & 3);  // 0..31
  const int m0 = bm * 128;
  const int n0 = bn * 128;

  const int t = threadIdx.x;
  const int lane = t & 63;
  const int wid = t >> 6;    // 4 waves
  const int wr = wid >> 1;   // 2 (M)
  const int wc = wid & 1;    // 2 (N)
  const int fr = lane & 15;
  const int hq = lane >> 4;  // k-quarter (16 int8)

  const int csw0 = (hq ^ (fr & 7)) * 16;
  const int csw1 = ((hq ^ 4) ^ (fr & 7)) * 16;

  // staging constants: A 16KB = 16 instr (4/wave), B 16KB = 16 instr (4/wave)
  int goffS[4], ldsS[4];
#pragma unroll
  for (int i = 0; i < 4; ++i) {
    const int srow = wid * 32 + i * 8 + (lane >> 3);  // 0..127
    const int sch = (lane & 7) ^ (srow & 7);          // inverse swizzle
    goffS[i] = srow * IN_F + sch * 16;
    ldsS[i] = (wid * 4 + i) * 1024;                   // wave-uniform
  }

  const char* Ag = (const char*)(xq + (size_t)m0 * IN_F);
  const char* Bg = (const char*)(wq + (size_t)n0 * IN_F);

  i32x4 iacc[4][4];
#pragma unroll
  for (int i = 0; i < 4; ++i)
#pragma unroll
    for (int j = 0; j < 4; ++j) iacc[i][j] = (i32x4){0, 0, 0, 0};

  i32x4 aF[4][2];
  i32x4 bF[4][2];

  // ---- prologue: stage tiles 0 (buf0), 1 (buf1); drain tile0.
  STAGE_T(0, 0);
  STAGE_T(1, 1);
  asm volatile("s_waitcnt vmcnt(8) lgkmcnt(0)" ::: "memory");
  __builtin_amdgcn_s_barrier();

  // ---- main loop: 32 K-tiles, bufs alternate.
#pragma unroll 1
  for (int it = 0; it < 16; ++it) {
    const int T = 2 * it;
    PHASE(0, T);
    PHASE(1, T + 1);
  }

  // ---- epilogue: out = xs[m]*Sw[n]*acc + bias[n]
  float swv[4], bv[4];
#pragma unroll
  for (int nf = 0; nf < 4; ++nf) {
    const int n = n0 + wc * 64 + nf * 16 + fr;
    swv[nf] = sw[n];
    bv[nf] = bias[n];
  }
#pragma unroll
  for (int mf = 0; mf < 4; ++mf) {
#pragma unroll
    for (int r = 0; r < 4; ++r) {
      const int m = m0 + wr * 64 + mf * 16 + hq * 4 + r;
      const float xsv = xs[m];
      float* o = out + (size_t)m * OUT_F + n0;
#pragma unroll
      for (int nf = 0; nf < 4; ++nf) {
        o[wc * 64 + nf * 16 + fr] =
            xsv * swv[nf] * (float)iacc[mf][nf][r] + bv[nf];
      }
    }
  }
}

// ---------------------------------------------------------------------------
extern "C" void kernel_launch(void* const* d_in, const int* in_sizes, int n_in,
                              void* d_out, int out_size, void* d_ws,
                              size_t ws_size, hipStream_t stream) {
  const float* x = (const float*)d_in[0];
  const int* qweight = (const int*)d_in[1];
  const int* qzeros = (const int*)d_in[2];
  const float* scales = (const float*)d_in[3];
  const float* bias = (const float*)d_in[4];
  float* out = (float*)d_out;

  int8_t* xq = (int8_t*)d_ws;                       // 32 MiB
  int8_t* wq = xq + (size_t)TOKENS * IN_F;          // +16 MiB
  float* xs = (float*)(wq + (size_t)OUT_F * IN_F);  // +32 KiB
  float* sw = xs + TOKENS;                          // +16 KiB

  (void)hipFuncSetAttribute(reinterpret_cast<const void*>(&k_gemm_i8),
                            hipFuncAttributeMaxDynamicSharedMemorySize, 65536);

  k_quant_x<<<TOKENS, 256, 0, stream>>>(x, xq, xs);
  k_requant_w8<<<OUT_F / 16, 256, 0, stream>>>(qweight, qzeros, scales, wq, sw);
  k_gemm_i8<<<(TOKENS / 128) * (OUT_F / 128), 256, 65536, stream>>>(
      xq, wq, sw, xs, bias, out);
}